// Round 1
// baseline (1278.758 us; speedup 1.0000x reference)
//
#include <hip/hip_runtime.h>
#include <hip/hip_bf16.h>

typedef __attribute__((ext_vector_type(8))) short short8;
typedef __attribute__((ext_vector_type(4))) float f32x4;

#define T_TOK 8192
#define DMODEL 1024
#define HFFN 4096
#define NEXP 4

__device__ __forceinline__ ushort f2b(float f) {
    __hip_bfloat16 h = __float2bfloat16(f);
    return __builtin_bit_cast(ushort, h);
}

__device__ __forceinline__ void glds16(const void* g, void* l) {
    __builtin_amdgcn_global_load_lds(
        (__attribute__((address_space(1))) void*)g,
        (__attribute__((address_space(3))) void*)l, 16, 0, 0);
}

// ---------------- gate: logits -> softmax -> top2 -> renorm -> dense [T,4] ----
__global__ void gate_kernel(const float* __restrict__ x, const float* __restrict__ gw,
                            float* __restrict__ gdense) {
    const int lane = threadIdx.x & 63;
    const int wid = threadIdx.x >> 6;
    const int t = blockIdx.x * 4 + wid;
    const float* xr = x + (size_t)t * DMODEL;
    float acc[4] = {0.f, 0.f, 0.f, 0.f};
    for (int d0 = lane * 4; d0 < DMODEL; d0 += 256) {
        float4 xv = *(const float4*)&xr[d0];
#pragma unroll
        for (int e = 0; e < 4; e++) {
            float4 wv = *(const float4*)&gw[e * DMODEL + d0];
            acc[e] += xv.x * wv.x + xv.y * wv.y + xv.z * wv.z + xv.w * wv.w;
        }
    }
#pragma unroll
    for (int e = 0; e < 4; e++)
#pragma unroll
        for (int s = 1; s < 64; s <<= 1) acc[e] += __shfl_xor(acc[e], s);
    if (lane == 0) {
        int i0 = 0; float v0 = acc[0];
#pragma unroll
        for (int e = 1; e < 4; e++) if (acc[e] > v0) { v0 = acc[e]; i0 = e; }
        int i1 = -1; float v1 = -INFINITY;
#pragma unroll
        for (int e = 0; e < 4; e++) if (e != i0 && acc[e] > v1) { v1 = acc[e]; i1 = e; }
        // softmax top-2 renormalized: w = exp(l_i)/ (exp(l_a)+exp(l_b))
        float e1 = expf(v1 - v0);
        float w0 = 1.0f / (1.0f + e1);
        float w1 = e1 / (1.0f + e1);
        float o[4] = {0.f, 0.f, 0.f, 0.f};
        o[i0] = w0; o[i1] = w1;
        *(float4*)&gdense[t * 4] = make_float4(o[0], o[1], o[2], o[3]);
    }
}

// ---------------- fp32 -> bf16 elementwise (4/thread) -------------------------
__global__ void cvt_bf16_4(const float* __restrict__ in, ushort* __restrict__ out, int n4) {
    int i = blockIdx.x * blockDim.x + threadIdx.x;
    if (i < n4) {
        float4 v = ((const float4*)in)[i];
        ushort4 o;
        o.x = f2b(v.x); o.y = f2b(v.y); o.z = f2b(v.z); o.w = f2b(v.w);
        ((ushort4*)out)[i] = o;
    }
}

// ---------------- fp32 [Kd][Nd] -> bf16 [Nd][Kd] (batched over z) -------------
__global__ void transpose_cvt(const float* __restrict__ in, ushort* __restrict__ out,
                              int Kd, int Nd) {
    __shared__ float tile[32][33];
    const size_t mat = (size_t)Kd * Nd;
    const float* ip = in + (size_t)blockIdx.z * mat;
    ushort* op = out + (size_t)blockIdx.z * mat;
    const int n0 = blockIdx.x * 32, k0 = blockIdx.y * 32;
    const int tx = threadIdx.x, ty = threadIdx.y;  // (32, 8)
#pragma unroll
    for (int j = 0; j < 4; j++)
        tile[ty + j * 8][tx] = ip[(size_t)(k0 + ty + j * 8) * Nd + n0 + tx];
    __syncthreads();
#pragma unroll
    for (int j = 0; j < 4; j++)
        op[(size_t)(n0 + ty + j * 8) * Kd + k0 + tx] = f2b(tile[tx][ty + j * 8]);
}

// ---------------- bf16 GEMM, B transposed ([N][K]), m97 structure -------------
// MODE 0: hout[t][c] = bf16( gelu(acc + bias[c]) )
// MODE 1: yout[t][c] += g(t) * (acc + bias[c]),  g = gate[t*4+expert] or 1.0
template <int MODE>
__launch_bounds__(256)
__global__ void gemm_bt_k(const ushort* __restrict__ A, const ushort* __restrict__ Bt,
                          int N, int Kd,
                          const float* __restrict__ bias,
                          ushort* __restrict__ hout, float* __restrict__ yout,
                          const float* __restrict__ gate, int expert) {
    constexpr int BM = 128, BN = 128, BK = 32;
    __shared__ ushort As[BM * BK];  // [row][k]
    __shared__ ushort Bs[BN * BK];  // [col][k]
    const int tid = threadIdx.x;
    const int lane = tid & 63, wid = tid >> 6;
    const int wrow = wid >> 1, wcol = wid & 1;
    const int row0 = blockIdx.y * BM, col0 = blockIdx.x * BN;

    f32x4 acc[4][4] = {};

    const int s_r = tid >> 2;             // staging row within 64-row chunk
    const int s_k = (tid & 3) * 8;        // staging k offset (8 bf16 = 16B)

    for (int k0 = 0; k0 < Kd; k0 += BK) {
#pragma unroll
        for (int i = 0; i < 2; i++) {
            glds16(&A[(size_t)(row0 + i * 64 + s_r) * Kd + k0 + s_k],
                   &As[i * 2048 + wid * 512]);
            glds16(&Bt[(size_t)(col0 + i * 64 + s_r) * Kd + k0 + s_k],
                   &Bs[i * 2048 + wid * 512]);
        }
        __syncthreads();
        const int lr = lane & 15, lk = (lane >> 4) * 8;
        short8 af[4], bf[4];
#pragma unroll
        for (int m = 0; m < 4; m++)
            af[m] = *(const short8*)&As[(wrow * 64 + m * 16 + lr) * BK + lk];
#pragma unroll
        for (int n = 0; n < 4; n++)
            bf[n] = *(const short8*)&Bs[(wcol * 64 + n * 16 + lr) * BK + lk];
#pragma unroll
        for (int m = 0; m < 4; m++)
#pragma unroll
            for (int n = 0; n < 4; n++)
                acc[m][n] = __builtin_amdgcn_mfma_f32_16x16x32_bf16(af[m], bf[n], acc[m][n], 0, 0, 0);
        __syncthreads();
    }

    // epilogue: C/D layout col = lane&15, row = (lane>>4)*4 + j  [verified]
    const int lr = lane & 15, lq = lane >> 4;
#pragma unroll
    for (int m = 0; m < 4; m++) {
        const int t_base = row0 + wrow * 64 + m * 16 + lq * 4;
#pragma unroll
        for (int n = 0; n < 4; n++) {
            const int c = col0 + wcol * 64 + n * 16 + lr;
            const float b = bias[c];
#pragma unroll
            for (int j = 0; j < 4; j++) {
                const int t = t_base + j;
                float v = acc[m][n][j] + b;
                if (MODE == 0) {
                    float gl = 0.5f * v * (1.0f + erff(v * 0.70710678118654752f));
                    hout[(size_t)t * N + c] = f2b(gl);
                } else {
                    float g = (expert >= 0) ? gate[t * 4 + expert] : 1.0f;
                    yout[(size_t)t * N + c] += g * v;
                }
            }
        }
    }
}

extern "C" void kernel_launch(void* const* d_in, const int* in_sizes, int n_in,
                              void* d_out, int out_size, void* d_ws, size_t ws_size,
                              hipStream_t stream) {
    const float* x      = (const float*)d_in[0];
    const float* gate_w = (const float*)d_in[1];
    const float* W1     = (const float*)d_in[2];
    const float* b1     = (const float*)d_in[3];
    const float* W2     = (const float*)d_in[4];
    const float* b2     = (const float*)d_in[5];
    const float* sW1    = (const float*)d_in[6];
    const float* sb1    = (const float*)d_in[7];
    const float* sW2    = (const float*)d_in[8];
    const float* sb2    = (const float*)d_in[9];
    float* out = (float*)d_out;

    char* ws = (char*)d_ws;
    size_t off = 0;
    auto alloc = [&](size_t bytes) {
        void* p = ws + off;
        off += (bytes + 255) & ~(size_t)255;
        return p;
    };
    float*  gdense = (float*)alloc((size_t)T_TOK * NEXP * 4);
    ushort* Xb     = (ushort*)alloc((size_t)T_TOK * DMODEL * 2);
    ushort* W1t    = (ushort*)alloc((size_t)NEXP * DMODEL * HFFN * 2);
    ushort* W2t    = (ushort*)alloc((size_t)NEXP * HFFN * DMODEL * 2);
    ushort* sW1t   = (ushort*)alloc((size_t)DMODEL * HFFN * 2);
    ushort* sW2t   = (ushort*)alloc((size_t)HFFN * DMODEL * 2);
    ushort* hbuf   = (ushort*)alloc((size_t)T_TOK * HFFN * 2);

    hipMemsetAsync(d_out, 0, (size_t)out_size * sizeof(float), stream);

    gate_kernel<<<T_TOK / 4, 256, 0, stream>>>(x, gate_w, gdense);

    cvt_bf16_4<<<(T_TOK * DMODEL / 4) / 256, 256, 0, stream>>>(x, Xb, T_TOK * DMODEL / 4);
    // W1 [E][D][H] -> W1t [E][H][D]
    transpose_cvt<<<dim3(HFFN / 32, DMODEL / 32, NEXP), dim3(32, 8), 0, stream>>>(W1, W1t, DMODEL, HFFN);
    // W2 [E][H][D] -> W2t [E][D][H]
    transpose_cvt<<<dim3(DMODEL / 32, HFFN / 32, NEXP), dim3(32, 8), 0, stream>>>(W2, W2t, HFFN, DMODEL);
    transpose_cvt<<<dim3(HFFN / 32, DMODEL / 32, 1), dim3(32, 8), 0, stream>>>(sW1, sW1t, DMODEL, HFFN);
    transpose_cvt<<<dim3(DMODEL / 32, HFFN / 32, 1), dim3(32, 8), 0, stream>>>(sW2, sW2t, HFFN, DMODEL);

    dim3 g1(HFFN / 128, T_TOK / 128);    // GEMM1: [T,H]
    dim3 g2(DMODEL / 128, T_TOK / 128);  // GEMM2: [T,D]
    for (int e = 0; e < NEXP; e++) {
        gemm_bt_k<0><<<g1, 256, 0, stream>>>(Xb, W1t + (size_t)e * DMODEL * HFFN,
                                             HFFN, DMODEL, b1 + (size_t)e * HFFN,
                                             hbuf, nullptr, nullptr, -1);
        gemm_bt_k<1><<<g2, 256, 0, stream>>>(hbuf, W2t + (size_t)e * HFFN * DMODEL,
                                             DMODEL, HFFN, b2 + (size_t)e * DMODEL,
                                             nullptr, out, gdense, e);
    }
    // shared expert
    gemm_bt_k<0><<<g1, 256, 0, stream>>>(Xb, sW1t, HFFN, DMODEL, sb1, hbuf, nullptr, nullptr, -1);
    gemm_bt_k<1><<<g2, 256, 0, stream>>>(hbuf, sW2t, DMODEL, HFFN, sb2, nullptr, out, nullptr, -1);
}

// Round 2
// 1260.025 us; speedup vs baseline: 1.0149x; 1.0149x over previous
//
#include <hip/hip_runtime.h>
#include <hip/hip_bf16.h>

typedef __attribute__((ext_vector_type(8))) short short8;
typedef __attribute__((ext_vector_type(4))) float f32x4;

#define T_TOK 8192
#define DMODEL 1024
#define HFFN 4096
#define NEXP 4

__device__ __forceinline__ ushort f2b(float f) {
    __hip_bfloat16 h = __float2bfloat16(f);
    return __builtin_bit_cast(ushort, h);
}

__device__ __forceinline__ void glds16(const void* g, void* l) {
    __builtin_amdgcn_global_load_lds(
        (__attribute__((address_space(1))) void*)g,
        (__attribute__((address_space(3))) void*)l, 16, 0, 0);
}

// ---------------- gate: logits -> softmax -> top2 -> renorm -> dense [T,4] ----
// Also builds per-expert token lists for routed dispatch.
__global__ void gate_kernel(const float* __restrict__ x, const float* __restrict__ gw,
                            float* __restrict__ gdense, int* __restrict__ counts,
                            int* __restrict__ lists) {
    const int lane = threadIdx.x & 63;
    const int wid = threadIdx.x >> 6;
    const int t = blockIdx.x * 4 + wid;
    const float* xr = x + (size_t)t * DMODEL;
    float acc[4] = {0.f, 0.f, 0.f, 0.f};
    for (int d0 = lane * 4; d0 < DMODEL; d0 += 256) {
        float4 xv = *(const float4*)&xr[d0];
#pragma unroll
        for (int e = 0; e < 4; e++) {
            float4 wv = *(const float4*)&gw[e * DMODEL + d0];
            acc[e] += xv.x * wv.x + xv.y * wv.y + xv.z * wv.z + xv.w * wv.w;
        }
    }
#pragma unroll
    for (int e = 0; e < 4; e++)
#pragma unroll
        for (int s = 1; s < 64; s <<= 1) acc[e] += __shfl_xor(acc[e], s);
    if (lane == 0) {
        int i0 = 0; float v0 = acc[0];
#pragma unroll
        for (int e = 1; e < 4; e++) if (acc[e] > v0) { v0 = acc[e]; i0 = e; }
        int i1 = -1; float v1 = -INFINITY;
#pragma unroll
        for (int e = 0; e < 4; e++) if (e != i0 && acc[e] > v1) { v1 = acc[e]; i1 = e; }
        float e1 = expf(v1 - v0);
        float w0 = 1.0f / (1.0f + e1);
        float w1 = e1 / (1.0f + e1);
        float o[4] = {0.f, 0.f, 0.f, 0.f};
        o[i0] = w0; o[i1] = w1;
        *(float4*)&gdense[t * 4] = make_float4(o[0], o[1], o[2], o[3]);
        int p0 = atomicAdd(&counts[i0], 1);
        lists[i0 * T_TOK + p0] = t;
        int p1 = atomicAdd(&counts[i1], 1);
        lists[i1 * T_TOK + p1] = t;
    }
}

// ---------------- fp32 -> bf16 elementwise (4/thread) -------------------------
__global__ void cvt_bf16_4(const float* __restrict__ in, ushort* __restrict__ out, int n4) {
    int i = blockIdx.x * blockDim.x + threadIdx.x;
    if (i < n4) {
        float4 v = ((const float4*)in)[i];
        ushort4 o;
        o.x = f2b(v.x); o.y = f2b(v.y); o.z = f2b(v.z); o.w = f2b(v.w);
        ((ushort4*)out)[i] = o;
    }
}

// ---------------- fp32 [Kd][Nd] -> bf16 [Nd][Kd] (batched over z) -------------
__global__ void transpose_cvt(const float* __restrict__ in, ushort* __restrict__ out,
                              int Kd, int Nd) {
    __shared__ float tile[32][33];
    const size_t mat = (size_t)Kd * Nd;
    const float* ip = in + (size_t)blockIdx.z * mat;
    ushort* op = out + (size_t)blockIdx.z * mat;
    const int n0 = blockIdx.x * 32, k0 = blockIdx.y * 32;
    const int tx = threadIdx.x, ty = threadIdx.y;  // (32, 8)
#pragma unroll
    for (int j = 0; j < 4; j++)
        tile[ty + j * 8][tx] = ip[(size_t)(k0 + ty + j * 8) * Nd + n0 + tx];
    __syncthreads();
#pragma unroll
    for (int j = 0; j < 4; j++)
        op[(size_t)(n0 + ty + j * 8) * Kd + k0 + tx] = f2b(tile[tx][ty + j * 8]);
}

// ---------------- bf16 GEMM, B transposed ([N][K]), m97 structure -------------
// MODE 0: hout[r][c] = bf16( gelu(acc + bias[c]) )   (GATHER: A rows via list)
// MODE 1: yout[list[r]][c] += gate[list[r]*4+expert] * (acc + bias[c])
// MODE 2: yout[r][c] = acc + bias[c]                 (dense store, shared expert)
template <int MODE, bool GATHER>
__launch_bounds__(256)
__global__ void gemm_bt_k(const ushort* __restrict__ A, const ushort* __restrict__ Bt,
                          int N, int Kd,
                          const float* __restrict__ bias,
                          ushort* __restrict__ hout, float* __restrict__ yout,
                          const float* __restrict__ gate, int expert,
                          const int* __restrict__ list, const int* __restrict__ cntp) {
    constexpr int BM = 128, BN = 128, BK = 32;
    __shared__ ushort As[BM * BK];  // [row][k]
    __shared__ ushort Bs[BN * BK];  // [col][k]
    const int cnt = cntp ? *cntp : T_TOK;
    const int row0 = blockIdx.y * BM;
    if (row0 >= cnt) return;
    const int tid = threadIdx.x;
    const int lane = tid & 63, wid = tid >> 6;
    const int wrow = wid >> 1, wcol = wid & 1;
    const int col0 = blockIdx.x * BN;

    f32x4 acc[4][4] = {};

    const int s_r = tid >> 2;             // staging row within 64-row chunk
    const int s_k = (tid & 3) * 8;        // staging k offset (8 bf16 = 16B)

    // Precompute A staging row pointers (gathered if routed).
    int gr0 = row0 + s_r, gr1 = row0 + 64 + s_r;
    size_t ar0, ar1;
    if (GATHER) {
        ar0 = (size_t)list[gr0 < cnt ? gr0 : cnt - 1];
        ar1 = (size_t)list[gr1 < cnt ? gr1 : cnt - 1];
    } else {
        ar0 = (size_t)gr0; ar1 = (size_t)gr1;
    }
    const ushort* Ap0 = A + ar0 * Kd + s_k;
    const ushort* Ap1 = A + ar1 * Kd + s_k;
    const ushort* Bp0 = Bt + (size_t)(col0 + s_r) * Kd + s_k;
    const ushort* Bp1 = Bt + (size_t)(col0 + 64 + s_r) * Kd + s_k;

    for (int k0 = 0; k0 < Kd; k0 += BK) {
        glds16(Ap0 + k0, &As[wid * 512]);
        glds16(Ap1 + k0, &As[2048 + wid * 512]);
        glds16(Bp0 + k0, &Bs[wid * 512]);
        glds16(Bp1 + k0, &Bs[2048 + wid * 512]);
        __syncthreads();
        const int lr = lane & 15, lk = (lane >> 4) * 8;
        short8 af[4], bf[4];
#pragma unroll
        for (int m = 0; m < 4; m++)
            af[m] = *(const short8*)&As[(wrow * 64 + m * 16 + lr) * BK + lk];
#pragma unroll
        for (int n = 0; n < 4; n++)
            bf[n] = *(const short8*)&Bs[(wcol * 64 + n * 16 + lr) * BK + lk];
#pragma unroll
        for (int m = 0; m < 4; m++)
#pragma unroll
            for (int n = 0; n < 4; n++)
                acc[m][n] = __builtin_amdgcn_mfma_f32_16x16x32_bf16(af[m], bf[n], acc[m][n], 0, 0, 0);
        __syncthreads();
    }

    // epilogue: C/D layout col = lane&15, row = (lane>>4)*4 + j  [verified]
    const int lr = lane & 15, lq = lane >> 4;
#pragma unroll
    for (int m = 0; m < 4; m++) {
        const int r_base = row0 + wrow * 64 + m * 16 + lq * 4;
#pragma unroll
        for (int n = 0; n < 4; n++) {
            const int c = col0 + wcol * 64 + n * 16 + lr;
            const float b = bias[c];
#pragma unroll
            for (int j = 0; j < 4; j++) {
                const int r = r_base + j;
                if (r >= cnt) continue;
                float v = acc[m][n][j] + b;
                if (MODE == 0) {
                    // tanh-approx GELU (error ~1e-3, below bf16 round-off of h)
                    float u = 1.5957691216057308f * (v + 0.044715f * v * v * v); // 2*sqrt(2/pi)
                    float e = __expf(u);
                    float th = 1.0f - __fdividef(2.0f, e + 1.0f);
                    hout[(size_t)r * N + c] = f2b(0.5f * v * (1.0f + th));
                } else if (MODE == 1) {
                    const int tok = list[r];
                    const float g = gate[tok * 4 + expert];
                    yout[(size_t)tok * N + c] += g * v;
                } else {
                    yout[(size_t)r * N + c] = v;
                }
            }
        }
    }
}

extern "C" void kernel_launch(void* const* d_in, const int* in_sizes, int n_in,
                              void* d_out, int out_size, void* d_ws, size_t ws_size,
                              hipStream_t stream) {
    const float* x      = (const float*)d_in[0];
    const float* gate_w = (const float*)d_in[1];
    const float* W1     = (const float*)d_in[2];
    const float* b1     = (const float*)d_in[3];
    const float* W2     = (const float*)d_in[4];
    const float* b2     = (const float*)d_in[5];
    const float* sW1    = (const float*)d_in[6];
    const float* sb1    = (const float*)d_in[7];
    const float* sW2    = (const float*)d_in[8];
    const float* sb2    = (const float*)d_in[9];
    float* out = (float*)d_out;

    char* ws = (char*)d_ws;
    size_t off = 0;
    auto alloc = [&](size_t bytes) {
        void* p = ws + off;
        off += (bytes + 255) & ~(size_t)255;
        return p;
    };
    float*  gdense = (float*)alloc((size_t)T_TOK * NEXP * 4);
    int*    counts = (int*)alloc(NEXP * 4);
    int*    lists  = (int*)alloc((size_t)NEXP * T_TOK * 4);
    ushort* Xb     = (ushort*)alloc((size_t)T_TOK * DMODEL * 2);
    ushort* W1t    = (ushort*)alloc((size_t)NEXP * DMODEL * HFFN * 2);
    ushort* W2t    = (ushort*)alloc((size_t)NEXP * HFFN * DMODEL * 2);
    ushort* sW1t   = (ushort*)alloc((size_t)DMODEL * HFFN * 2);
    ushort* sW2t   = (ushort*)alloc((size_t)HFFN * DMODEL * 2);
    ushort* hbuf   = (ushort*)alloc((size_t)T_TOK * HFFN * 2);

    hipMemsetAsync(counts, 0, NEXP * sizeof(int), stream);

    gate_kernel<<<T_TOK / 4, 256, 0, stream>>>(x, gate_w, gdense, counts, lists);

    cvt_bf16_4<<<(T_TOK * DMODEL / 4) / 256, 256, 0, stream>>>(x, Xb, T_TOK * DMODEL / 4);
    // W1 [E][D][H] -> W1t [E][H][D]
    transpose_cvt<<<dim3(HFFN / 32, DMODEL / 32, NEXP), dim3(32, 8), 0, stream>>>(W1, W1t, DMODEL, HFFN);
    // W2 [E][H][D] -> W2t [E][D][H]
    transpose_cvt<<<dim3(DMODEL / 32, HFFN / 32, NEXP), dim3(32, 8), 0, stream>>>(W2, W2t, HFFN, DMODEL);
    transpose_cvt<<<dim3(HFFN / 32, DMODEL / 32, 1), dim3(32, 8), 0, stream>>>(sW1, sW1t, DMODEL, HFFN);
    transpose_cvt<<<dim3(DMODEL / 32, HFFN / 32, 1), dim3(32, 8), 0, stream>>>(sW2, sW2t, HFFN, DMODEL);

    dim3 g1(HFFN / 128, T_TOK / 128);    // GEMM1: [rows, H]
    dim3 g2(DMODEL / 128, T_TOK / 128);  // GEMM2: [rows, D]

    // Shared expert first: GEMM2 stores (initializes out), experts accumulate after.
    gemm_bt_k<0, false><<<g1, 256, 0, stream>>>(Xb, sW1t, HFFN, DMODEL, sb1,
                                                hbuf, nullptr, nullptr, -1, nullptr, nullptr);
    gemm_bt_k<2, false><<<g2, 256, 0, stream>>>(hbuf, sW2t, DMODEL, HFFN, sb2,
                                                nullptr, out, nullptr, -1, nullptr, nullptr);

    for (int e = 0; e < NEXP; e++) {
        gemm_bt_k<0, true><<<g1, 256, 0, stream>>>(Xb, W1t + (size_t)e * DMODEL * HFFN,
                                                   HFFN, DMODEL, b1 + (size_t)e * HFFN,
                                                   hbuf, nullptr, nullptr, -1,
                                                   lists + (size_t)e * T_TOK, counts + e);
        gemm_bt_k<1, false><<<g2, 256, 0, stream>>>(hbuf, W2t + (size_t)e * HFFN * DMODEL,
                                                    DMODEL, HFFN, b2 + (size_t)e * DMODEL,
                                                    nullptr, out, gdense, e,
                                                    lists + (size_t)e * T_TOK, counts + e);
    }
}

// Round 3
// 1083.109 us; speedup vs baseline: 1.1806x; 1.1633x over previous
//
#include <hip/hip_runtime.h>
#include <hip/hip_bf16.h>

typedef __attribute__((ext_vector_type(8))) short short8;
typedef __attribute__((ext_vector_type(4))) float f32x4;

#define T_TOK 8192
#define DMODEL 1024
#define HFFN 4096
#define NEXP 4

__device__ __forceinline__ ushort f2b(float f) {
    __hip_bfloat16 h = __float2bfloat16(f);
    return __builtin_bit_cast(ushort, h);
}

__device__ __forceinline__ void glds16(const void* g, void* l) {
    __builtin_amdgcn_global_load_lds(
        (__attribute__((address_space(1))) void*)g,
        (__attribute__((address_space(3))) void*)l, 16, 0, 0);
}

// ---------------- gate + x->bf16 fusion + ballot-aggregated routing ----------
// 32 tokens/block (8 per wave). gate_w held in registers (64 VGPR).
// List building: wave 0 ballots the block's 32 tokens per expert -> 4 atomics
// per block (vs 2 per token before: 16384 -> 1024 contended atomics).
__global__ __launch_bounds__(256) void gate_kernel(
        const float* __restrict__ x, const float* __restrict__ gw,
        ushort* __restrict__ Xb, float* __restrict__ gdense,
        int* __restrict__ counts, int* __restrict__ lists) {
    const int lane = threadIdx.x & 63;
    const int w = threadIdx.x >> 6;
    __shared__ int top2s[32];

    // Preload gate_w columns this lane needs: d = p*256 + lane*4, p=0..3
    float4 wv[4][4];
#pragma unroll
    for (int p = 0; p < 4; p++)
#pragma unroll
        for (int e = 0; e < 4; e++)
            wv[p][e] = *(const float4*)&gw[e * DMODEL + p * 256 + lane * 4];

    const int t0 = blockIdx.x * 32 + w * 8;
#pragma unroll
    for (int i = 0; i < 8; i++) {
        const int t = t0 + i;
        const float* xr = x + (size_t)t * DMODEL;
        ushort* xbr = Xb + (size_t)t * DMODEL;
        float acc[4] = {0.f, 0.f, 0.f, 0.f};
#pragma unroll
        for (int p = 0; p < 4; p++) {
            float4 xv = *(const float4*)&xr[p * 256 + lane * 4];
            ushort4 o;
            o.x = f2b(xv.x); o.y = f2b(xv.y); o.z = f2b(xv.z); o.w = f2b(xv.w);
            *(ushort4*)&xbr[p * 256 + lane * 4] = o;
#pragma unroll
            for (int e = 0; e < 4; e++)
                acc[e] += xv.x * wv[p][e].x + xv.y * wv[p][e].y +
                          xv.z * wv[p][e].z + xv.w * wv[p][e].w;
        }
#pragma unroll
        for (int e = 0; e < 4; e++)
#pragma unroll
            for (int s = 1; s < 64; s <<= 1) acc[e] += __shfl_xor(acc[e], s);
        if (lane == 0) {
            int i0 = 0; float v0 = acc[0];
#pragma unroll
            for (int e = 1; e < 4; e++) if (acc[e] > v0) { v0 = acc[e]; i0 = e; }
            int i1 = -1; float v1 = -INFINITY;
#pragma unroll
            for (int e = 0; e < 4; e++) if (e != i0 && acc[e] > v1) { v1 = acc[e]; i1 = e; }
            float e1 = expf(v1 - v0);
            float w0 = 1.0f / (1.0f + e1);
            float w1 = e1 / (1.0f + e1);
            float o[4] = {0.f, 0.f, 0.f, 0.f};
            o[i0] = w0; o[i1] = w1;
            *(float4*)&gdense[t * 4] = make_float4(o[0], o[1], o[2], o[3]);
            top2s[w * 8 + i] = i0 | (i1 << 4);
        }
    }
    __syncthreads();
    if (w == 0) {
        int i0 = -1, i1 = -1;
        if (lane < 32) {
            const int pk = top2s[lane];
            i0 = pk & 15; i1 = pk >> 4;
        }
        const unsigned long long below = (1ull << lane) - 1;
        const int t = blockIdx.x * 32 + lane;
#pragma unroll
        for (int e = 0; e < 4; e++) {
            unsigned long long m0 = __ballot(i0 == e);
            unsigned long long m1 = __ballot(i1 == e);
            const int c0 = __popcll(m0);
            const int c1 = __popcll(m1);
            int base = 0;
            if (lane == 0 && (c0 + c1) > 0) base = atomicAdd(&counts[e], c0 + c1);
            base = __shfl(base, 0);
            if (i0 == e) lists[e * T_TOK + base + __popcll(m0 & below)] = t;
            if (i1 == e) lists[e * T_TOK + base + c0 + __popcll(m1 & below)] = t;
        }
    }
}

// ---------------- fp32 [Kd][Nd] -> bf16 [Nd][Kd] (batched over z) -------------
__global__ void transpose_cvt(const float* __restrict__ in, ushort* __restrict__ out,
                              int Kd, int Nd) {
    __shared__ float tile[32][33];
    const size_t mat = (size_t)Kd * Nd;
    const float* ip = in + (size_t)blockIdx.z * mat;
    ushort* op = out + (size_t)blockIdx.z * mat;
    const int n0 = blockIdx.x * 32, k0 = blockIdx.y * 32;
    const int tx = threadIdx.x, ty = threadIdx.y;  // (32, 8)
#pragma unroll
    for (int j = 0; j < 4; j++)
        tile[ty + j * 8][tx] = ip[(size_t)(k0 + ty + j * 8) * Nd + n0 + tx];
    __syncthreads();
#pragma unroll
    for (int j = 0; j < 4; j++)
        op[(size_t)(n0 + ty + j * 8) * Kd + k0 + tx] = f2b(tile[tx][ty + j * 8]);
}

// ---------------- bf16 GEMM, B transposed ([N][K]), m97 structure -------------
// MODE 0: hout[r][c] = bf16( gelu(acc + bias[c]) )   (GATHER: A rows via list)
// MODE 1: yout[list[r]][c] += gate[list[r]*4+expert] * (acc + bias[c])
// MODE 2: yout[r][c] = acc + bias[c]                 (dense store, shared expert)
template <int MODE, bool GATHER>
__launch_bounds__(256)
__global__ void gemm_bt_k(const ushort* __restrict__ A, const ushort* __restrict__ Bt,
                          int N, int Kd,
                          const float* __restrict__ bias,
                          ushort* __restrict__ hout, float* __restrict__ yout,
                          const float* __restrict__ gate, int expert,
                          const int* __restrict__ list, const int* __restrict__ cntp) {
    constexpr int BM = 128, BN = 128, BK = 32;
    __shared__ ushort As[BM * BK];  // [row][k]
    __shared__ ushort Bs[BN * BK];  // [col][k]
    const int cnt = cntp ? *cntp : T_TOK;
    const int row0 = blockIdx.y * BM;
    if (row0 >= cnt) return;
    const int tid = threadIdx.x;
    const int lane = tid & 63, wid = tid >> 6;
    const int wrow = wid >> 1, wcol = wid & 1;
    const int col0 = blockIdx.x * BN;

    f32x4 acc[4][4] = {};

    const int s_r = tid >> 2;             // staging row within 64-row chunk
    const int s_k = (tid & 3) * 8;        // staging k offset (8 bf16 = 16B)

    int gr0 = row0 + s_r, gr1 = row0 + 64 + s_r;
    size_t ar0, ar1;
    if (GATHER) {
        ar0 = (size_t)list[gr0 < cnt ? gr0 : cnt - 1];
        ar1 = (size_t)list[gr1 < cnt ? gr1 : cnt - 1];
    } else {
        ar0 = (size_t)gr0; ar1 = (size_t)gr1;
    }
    const ushort* Ap0 = A + ar0 * Kd + s_k;
    const ushort* Ap1 = A + ar1 * Kd + s_k;
    const ushort* Bp0 = Bt + (size_t)(col0 + s_r) * Kd + s_k;
    const ushort* Bp1 = Bt + (size_t)(col0 + 64 + s_r) * Kd + s_k;

    for (int k0 = 0; k0 < Kd; k0 += BK) {
        glds16(Ap0 + k0, &As[wid * 512]);
        glds16(Ap1 + k0, &As[2048 + wid * 512]);
        glds16(Bp0 + k0, &Bs[wid * 512]);
        glds16(Bp1 + k0, &Bs[2048 + wid * 512]);
        __syncthreads();
        const int lr = lane & 15, lk = (lane >> 4) * 8;
        short8 af[4], bf[4];
#pragma unroll
        for (int m = 0; m < 4; m++)
            af[m] = *(const short8*)&As[(wrow * 64 + m * 16 + lr) * BK + lk];
#pragma unroll
        for (int n = 0; n < 4; n++)
            bf[n] = *(const short8*)&Bs[(wcol * 64 + n * 16 + lr) * BK + lk];
#pragma unroll
        for (int m = 0; m < 4; m++)
#pragma unroll
            for (int n = 0; n < 4; n++)
                acc[m][n] = __builtin_amdgcn_mfma_f32_16x16x32_bf16(af[m], bf[n], acc[m][n], 0, 0, 0);
        __syncthreads();
    }

    // epilogue: C/D layout col = lane&15, row = (lane>>4)*4 + j  [verified]
    const int lr = lane & 15, lq = lane >> 4;
#pragma unroll
    for (int m = 0; m < 4; m++) {
        const int r_base = row0 + wrow * 64 + m * 16 + lq * 4;
#pragma unroll
        for (int n = 0; n < 4; n++) {
            const int c = col0 + wcol * 64 + n * 16 + lr;
            const float b = bias[c];
#pragma unroll
            for (int j = 0; j < 4; j++) {
                const int r = r_base + j;
                if (r >= cnt) continue;
                float v = acc[m][n][j] + b;
                if (MODE == 0) {
                    // tanh-approx GELU (error ~1e-3, below bf16 round-off of h)
                    float u = 1.5957691216057308f * (v + 0.044715f * v * v * v); // 2*sqrt(2/pi)
                    float e = __expf(u);
                    float th = 1.0f - __fdividef(2.0f, e + 1.0f);
                    hout[(size_t)r * N + c] = f2b(0.5f * v * (1.0f + th));
                } else if (MODE == 1) {
                    const int tok = list[r];
                    const float g = gate[tok * 4 + expert];
                    yout[(size_t)tok * N + c] += g * v;
                } else {
                    yout[(size_t)r * N + c] = v;
                }
            }
        }
    }
}

extern "C" void kernel_launch(void* const* d_in, const int* in_sizes, int n_in,
                              void* d_out, int out_size, void* d_ws, size_t ws_size,
                              hipStream_t stream) {
    const float* x      = (const float*)d_in[0];
    const float* gate_w = (const float*)d_in[1];
    const float* W1     = (const float*)d_in[2];
    const float* b1     = (const float*)d_in[3];
    const float* W2     = (const float*)d_in[4];
    const float* b2     = (const float*)d_in[5];
    const float* sW1    = (const float*)d_in[6];
    const float* sb1    = (const float*)d_in[7];
    const float* sW2    = (const float*)d_in[8];
    const float* sb2    = (const float*)d_in[9];
    float* out = (float*)d_out;

    char* ws = (char*)d_ws;
    size_t off = 0;
    auto alloc = [&](size_t bytes) {
        void* p = ws + off;
        off += (bytes + 255) & ~(size_t)255;
        return p;
    };
    float*  gdense = (float*)alloc((size_t)T_TOK * NEXP * 4);
    int*    counts = (int*)alloc(NEXP * 4);
    int*    lists  = (int*)alloc((size_t)NEXP * T_TOK * 4);
    ushort* Xb     = (ushort*)alloc((size_t)T_TOK * DMODEL * 2);
    ushort* W1t    = (ushort*)alloc((size_t)NEXP * DMODEL * HFFN * 2);
    ushort* W2t    = (ushort*)alloc((size_t)NEXP * HFFN * DMODEL * 2);
    ushort* sW1t   = (ushort*)alloc((size_t)DMODEL * HFFN * 2);
    ushort* sW2t   = (ushort*)alloc((size_t)HFFN * DMODEL * 2);
    ushort* hbuf   = (ushort*)alloc((size_t)T_TOK * HFFN * 2);

    hipMemsetAsync(counts, 0, NEXP * sizeof(int), stream);

    // gate + fused x->bf16 conversion + routing lists
    gate_kernel<<<T_TOK / 32, 256, 0, stream>>>(x, gate_w, Xb, gdense, counts, lists);

    // W1 [E][D][H] -> W1t [E][H][D]
    transpose_cvt<<<dim3(HFFN / 32, DMODEL / 32, NEXP), dim3(32, 8), 0, stream>>>(W1, W1t, DMODEL, HFFN);
    // W2 [E][H][D] -> W2t [E][D][H]
    transpose_cvt<<<dim3(DMODEL / 32, HFFN / 32, NEXP), dim3(32, 8), 0, stream>>>(W2, W2t, HFFN, DMODEL);
    transpose_cvt<<<dim3(HFFN / 32, DMODEL / 32, 1), dim3(32, 8), 0, stream>>>(sW1, sW1t, DMODEL, HFFN);
    transpose_cvt<<<dim3(DMODEL / 32, HFFN / 32, 1), dim3(32, 8), 0, stream>>>(sW2, sW2t, HFFN, DMODEL);

    dim3 g1(HFFN / 128, T_TOK / 128);    // GEMM1: [rows, H]
    dim3 g2(DMODEL / 128, T_TOK / 128);  // GEMM2: [rows, D]

    // Shared expert first: GEMM2 stores (initializes out), experts accumulate after.
    gemm_bt_k<0, false><<<g1, 256, 0, stream>>>(Xb, sW1t, HFFN, DMODEL, sb1,
                                                hbuf, nullptr, nullptr, -1, nullptr, nullptr);
    gemm_bt_k<2, false><<<g2, 256, 0, stream>>>(hbuf, sW2t, DMODEL, HFFN, sb2,
                                                nullptr, out, nullptr, -1, nullptr, nullptr);

    for (int e = 0; e < NEXP; e++) {
        gemm_bt_k<0, true><<<g1, 256, 0, stream>>>(Xb, W1t + (size_t)e * DMODEL * HFFN,
                                                   HFFN, DMODEL, b1 + (size_t)e * HFFN,
                                                   hbuf, nullptr, nullptr, -1,
                                                   lists + (size_t)e * T_TOK, counts + e);
        gemm_bt_k<1, false><<<g2, 256, 0, stream>>>(hbuf, W2t + (size_t)e * HFFN * DMODEL,
                                                    DMODEL, HFFN, b2 + (size_t)e * DMODEL,
                                                    nullptr, out, gdense, e,
                                                    lists + (size_t)e * T_TOK, counts + e);
    }
}

// Round 4
// 922.270 us; speedup vs baseline: 1.3865x; 1.1744x over previous
//
#include <hip/hip_runtime.h>
#include <hip/hip_bf16.h>

typedef __attribute__((ext_vector_type(8))) short short8;
typedef __attribute__((ext_vector_type(4))) float f32x4;

#define T_TOK 8192
#define DMODEL 1024
#define HFFN 4096
#define NEXP 4

__device__ __forceinline__ ushort f2b(float f) {
    __hip_bfloat16 h = __float2bfloat16(f);
    return __builtin_bit_cast(ushort, h);
}

__device__ __forceinline__ void glds16(const void* g, void* l) {
    __builtin_amdgcn_global_load_lds(
        (__attribute__((address_space(1))) void*)g,
        (__attribute__((address_space(3))) void*)l, 16, 0, 0);
}

// ---------------- gate + x->bf16 fusion + ballot-aggregated routing ----------
__global__ __launch_bounds__(256) void gate_kernel(
        const float* __restrict__ x, const float* __restrict__ gw,
        ushort* __restrict__ Xb, float* __restrict__ gdense,
        int* __restrict__ counts, int* __restrict__ lists) {
    const int lane = threadIdx.x & 63;
    const int w = threadIdx.x >> 6;
    __shared__ int top2s[32];

    float4 wv[4][4];
#pragma unroll
    for (int p = 0; p < 4; p++)
#pragma unroll
        for (int e = 0; e < 4; e++)
            wv[p][e] = *(const float4*)&gw[e * DMODEL + p * 256 + lane * 4];

    const int t0 = blockIdx.x * 32 + w * 8;
#pragma unroll
    for (int i = 0; i < 8; i++) {
        const int t = t0 + i;
        const float* xr = x + (size_t)t * DMODEL;
        ushort* xbr = Xb + (size_t)t * DMODEL;
        float acc[4] = {0.f, 0.f, 0.f, 0.f};
#pragma unroll
        for (int p = 0; p < 4; p++) {
            float4 xv = *(const float4*)&xr[p * 256 + lane * 4];
            ushort4 o;
            o.x = f2b(xv.x); o.y = f2b(xv.y); o.z = f2b(xv.z); o.w = f2b(xv.w);
            *(ushort4*)&xbr[p * 256 + lane * 4] = o;
#pragma unroll
            for (int e = 0; e < 4; e++)
                acc[e] += xv.x * wv[p][e].x + xv.y * wv[p][e].y +
                          xv.z * wv[p][e].z + xv.w * wv[p][e].w;
        }
#pragma unroll
        for (int e = 0; e < 4; e++)
#pragma unroll
            for (int s = 1; s < 64; s <<= 1) acc[e] += __shfl_xor(acc[e], s);
        if (lane == 0) {
            int i0 = 0; float v0 = acc[0];
#pragma unroll
            for (int e = 1; e < 4; e++) if (acc[e] > v0) { v0 = acc[e]; i0 = e; }
            int i1 = -1; float v1 = -INFINITY;
#pragma unroll
            for (int e = 0; e < 4; e++) if (e != i0 && acc[e] > v1) { v1 = acc[e]; i1 = e; }
            float e1 = expf(v1 - v0);
            float w0 = 1.0f / (1.0f + e1);
            float w1 = e1 / (1.0f + e1);
            float o[4] = {0.f, 0.f, 0.f, 0.f};
            o[i0] = w0; o[i1] = w1;
            *(float4*)&gdense[t * 4] = make_float4(o[0], o[1], o[2], o[3]);
            top2s[w * 8 + i] = i0 | (i1 << 4);
        }
    }
    __syncthreads();
    if (w == 0) {
        int i0 = -1, i1 = -1;
        if (lane < 32) {
            const int pk = top2s[lane];
            i0 = pk & 15; i1 = pk >> 4;
        }
        const unsigned long long below = (1ull << lane) - 1;
        const int t = blockIdx.x * 32 + lane;
#pragma unroll
        for (int e = 0; e < 4; e++) {
            unsigned long long m0 = __ballot(i0 == e);
            unsigned long long m1 = __ballot(i1 == e);
            const int c0 = __popcll(m0);
            const int c1 = __popcll(m1);
            int base = 0;
            if (lane == 0 && (c0 + c1) > 0) base = atomicAdd(&counts[e], c0 + c1);
            base = __shfl(base, 0);
            if (i0 == e) lists[e * T_TOK + base + __popcll(m0 & below)] = t;
            if (i1 == e) lists[e * T_TOK + base + c0 + __popcll(m1 & below)] = t;
        }
    }
}

// ---------------- fp32 [Kd][Nd] -> bf16 [Nd][Kd] (batched over z) -------------
__global__ void transpose_cvt(const float* __restrict__ in, ushort* __restrict__ out,
                              int Kd, int Nd) {
    __shared__ float tile[32][33];
    const size_t mat = (size_t)Kd * Nd;
    const float* ip = in + (size_t)blockIdx.z * mat;
    ushort* op = out + (size_t)blockIdx.z * mat;
    const int n0 = blockIdx.x * 32, k0 = blockIdx.y * 32;
    const int tx = threadIdx.x, ty = threadIdx.y;  // (32, 8)
#pragma unroll
    for (int j = 0; j < 4; j++)
        tile[ty + j * 8][tx] = ip[(size_t)(k0 + ty + j * 8) * Nd + n0 + tx];
    __syncthreads();
#pragma unroll
    for (int j = 0; j < 4; j++)
        op[(size_t)(n0 + ty + j * 8) * Kd + k0 + tx] = f2b(tile[tx][ty + j * 8]);
}

// ---------------- bf16 GEMM, B^T layout, 2-phase pipelined (T3-minimum) -------
// MODE 0: hout[r][c] = bf16( gelu(acc + bias[c]) )   (GATHER: A rows via list)
// MODE 1: yout[list[r]][c] += gate[list[r]*4+expert] * (acc + bias[c])
// MODE 2: yout[r][c] = acc + bias[c]
template <int MODE, bool GATHER, int BN>
__launch_bounds__(256)
__global__ void gemm_bt_k(const ushort* __restrict__ A, const ushort* __restrict__ Bt,
                          int N, int Kd,
                          const float* __restrict__ bias,
                          ushort* __restrict__ hout, float* __restrict__ yout,
                          const float* __restrict__ gate, int expert,
                          const int* __restrict__ list, const int* __restrict__ cntp) {
    constexpr int BM = 128, BK = 32;
    constexpr int MW = (BN == 128) ? 4 : 2;   // 16-row m-frags per wave
    constexpr int NW = 4;                     // 16-col n-frags per wave
    __shared__ ushort As[2][BM * BK];
    __shared__ ushort Bs[2][BN * BK];
    const int cnt = cntp ? *cntp : T_TOK;
    const int row0 = blockIdx.y * BM;
    if (row0 >= cnt) return;
    const int tid = threadIdx.x;
    const int lane = tid & 63, wid = tid >> 6;
    const int rowbase = (BN == 128) ? (wid >> 1) * 64 : wid * 32;
    const int colbase = (BN == 128) ? (wid & 1) * 64 : 0;
    const int col0 = blockIdx.x * BN;

    const int s_r = tid >> 2;             // staging row (0..63 within chunk)
    const int s_k = (tid & 3) * 8;        // staging k offset (8 bf16 = 16B)

    int gr0 = row0 + s_r, gr1 = row0 + 64 + s_r;
    size_t ar0, ar1;
    if (GATHER) {
        ar0 = (size_t)list[gr0 < cnt ? gr0 : cnt - 1];
        ar1 = (size_t)list[gr1 < cnt ? gr1 : cnt - 1];
    } else {
        ar0 = (size_t)gr0; ar1 = (size_t)gr1;
    }
    const ushort* Ap0 = A + ar0 * Kd + s_k;
    const ushort* Ap1 = A + ar1 * Kd + s_k;
    const ushort* Bp0 = Bt + (size_t)(col0 + s_r) * Kd + s_k;
    const ushort* Bp1 = Bt + (size_t)(col0 + 64 + s_r) * Kd + s_k;  // BN==128 only

    auto stage = [&](int buf, int k0) {
        glds16(Ap0 + k0, &As[buf][wid * 512]);
        glds16(Ap1 + k0, &As[buf][2048 + wid * 512]);
        glds16(Bp0 + k0, &Bs[buf][wid * 512]);
        if (BN == 128) glds16(Bp1 + k0, &Bs[buf][2048 + wid * 512]);
    };

    f32x4 acc[MW][NW] = {};
    const int lr = lane & 15, lk = (lane >> 4) * 8;

    auto compute = [&](int buf) {
        short8 af[MW], bf[NW];
#pragma unroll
        for (int m = 0; m < MW; m++)
            af[m] = *(const short8*)&As[buf][(rowbase + m * 16 + lr) * BK + lk];
#pragma unroll
        for (int n = 0; n < NW; n++)
            bf[n] = *(const short8*)&Bs[buf][(colbase + n * 16 + lr) * BK + lk];
#pragma unroll
        for (int m = 0; m < MW; m++)
#pragma unroll
            for (int n = 0; n < NW; n++)
                acc[m][n] = __builtin_amdgcn_mfma_f32_16x16x32_bf16(af[m], bf[n], acc[m][n], 0, 0, 0);
    };

    // 2-phase pipeline: STAGE(t+1) issued BEFORE compute(t); one barrier/K-step.
    stage(0, 0);
    __syncthreads();
    int cur = 0;
    const int nk = Kd / BK;
    for (int t = 0; t < nk - 1; ++t) {
        stage(cur ^ 1, (t + 1) * BK);
        compute(cur);
        __syncthreads();   // drains vmcnt(0)+lgkmcnt(0): next buffer ready, this one free
        cur ^= 1;
    }
    compute(cur);

    // epilogue: C/D layout col = lane&15, row = (lane>>4)*4 + j  [verified]
    const int lq = lane >> 4;
#pragma unroll
    for (int m = 0; m < MW; m++) {
        const int r_base = row0 + rowbase + m * 16 + lq * 4;
#pragma unroll
        for (int n = 0; n < NW; n++) {
            const int c = col0 + colbase + n * 16 + lr;
            const float b = bias[c];
#pragma unroll
            for (int j = 0; j < 4; j++) {
                const int r = r_base + j;
                if (r >= cnt) continue;
                float v = acc[m][n][j] + b;
                if (MODE == 0) {
                    float u = 1.5957691216057308f * (v + 0.044715f * v * v * v);
                    float e = __expf(u);
                    float th = 1.0f - __fdividef(2.0f, e + 1.0f);
                    hout[(size_t)r * N + c] = f2b(0.5f * v * (1.0f + th));
                } else if (MODE == 1) {
                    const int tok = list[r];
                    const float g = gate[tok * 4 + expert];
                    yout[(size_t)tok * N + c] += g * v;
                } else {
                    yout[(size_t)r * N + c] = v;
                }
            }
        }
    }
}

extern "C" void kernel_launch(void* const* d_in, const int* in_sizes, int n_in,
                              void* d_out, int out_size, void* d_ws, size_t ws_size,
                              hipStream_t stream) {
    const float* x      = (const float*)d_in[0];
    const float* gate_w = (const float*)d_in[1];
    const float* W1     = (const float*)d_in[2];
    const float* b1     = (const float*)d_in[3];
    const float* W2     = (const float*)d_in[4];
    const float* b2     = (const float*)d_in[5];
    const float* sW1    = (const float*)d_in[6];
    const float* sb1    = (const float*)d_in[7];
    const float* sW2    = (const float*)d_in[8];
    const float* sb2    = (const float*)d_in[9];
    float* out = (float*)d_out;

    char* ws = (char*)d_ws;
    size_t off = 0;
    auto alloc = [&](size_t bytes) {
        void* p = ws + off;
        off += (bytes + 255) & ~(size_t)255;
        return p;
    };
    float*  gdense = (float*)alloc((size_t)T_TOK * NEXP * 4);
    int*    counts = (int*)alloc(NEXP * 4);
    int*    lists  = (int*)alloc((size_t)NEXP * T_TOK * 4);
    ushort* Xb     = (ushort*)alloc((size_t)T_TOK * DMODEL * 2);
    ushort* W1t    = (ushort*)alloc((size_t)NEXP * DMODEL * HFFN * 2);
    ushort* W2t    = (ushort*)alloc((size_t)NEXP * HFFN * DMODEL * 2);
    ushort* sW1t   = (ushort*)alloc((size_t)DMODEL * HFFN * 2);
    ushort* sW2t   = (ushort*)alloc((size_t)HFFN * DMODEL * 2);
    ushort* hbuf   = (ushort*)alloc((size_t)T_TOK * HFFN * 2);

    hipMemsetAsync(counts, 0, NEXP * sizeof(int), stream);

    gate_kernel<<<T_TOK / 32, 256, 0, stream>>>(x, gate_w, Xb, gdense, counts, lists);

    transpose_cvt<<<dim3(HFFN / 32, DMODEL / 32, NEXP), dim3(32, 8), 0, stream>>>(W1, W1t, DMODEL, HFFN);
    transpose_cvt<<<dim3(DMODEL / 32, HFFN / 32, NEXP), dim3(32, 8), 0, stream>>>(W2, W2t, HFFN, DMODEL);
    transpose_cvt<<<dim3(HFFN / 32, DMODEL / 32, 1), dim3(32, 8), 0, stream>>>(sW1, sW1t, DMODEL, HFFN);
    transpose_cvt<<<dim3(DMODEL / 32, HFFN / 32, 1), dim3(32, 8), 0, stream>>>(sW2, sW2t, HFFN, DMODEL);

    dim3 g1(HFFN / 128, T_TOK / 128);   // GEMM1: BN=128
    dim3 g2(DMODEL / 64, T_TOK / 128);  // GEMM2: BN=64 (grid-starvation fix)

    // Shared expert first: GEMM2 stores (initializes out), experts accumulate after.
    gemm_bt_k<0, false, 128><<<g1, 256, 0, stream>>>(Xb, sW1t, HFFN, DMODEL, sb1,
                                                     hbuf, nullptr, nullptr, -1, nullptr, nullptr);
    gemm_bt_k<2, false, 64><<<g2, 256, 0, stream>>>(hbuf, sW2t, DMODEL, HFFN, sb2,
                                                    nullptr, out, nullptr, -1, nullptr, nullptr);

    for (int e = 0; e < NEXP; e++) {
        gemm_bt_k<0, true, 128><<<g1, 256, 0, stream>>>(Xb, W1t + (size_t)e * DMODEL * HFFN,
                                                        HFFN, DMODEL, b1 + (size_t)e * HFFN,
                                                        hbuf, nullptr, nullptr, -1,
                                                        lists + (size_t)e * T_TOK, counts + e);
        gemm_bt_k<1, false, 64><<<g2, 256, 0, stream>>>(hbuf, W2t + (size_t)e * HFFN * DMODEL,
                                                        DMODEL, HFFN, b2 + (size_t)e * DMODEL,
                                                        nullptr, out, gdense, e,
                                                        lists + (size_t)e * T_TOK, counts + e);
    }
}